// Round 8
// baseline (454.887 us; speedup 1.0000x reference)
//
#include <hip/hip_runtime.h>

namespace {
constexpr int HIN = 130, WIN = 130;
constexpr int HH = 128, WW = 128;
constexpr int C = 128, CR = 32, B = 8;
constexpr int CHW = HIN * WIN;   // 16900

// Fold the two matvecs: M = W_kern @ W_reduce  (72 x 128), stored transposed
// MT[128][72]; b2 = W_kern @ b_reduce + b_kern. 9216 dots of length 32.
__global__ void build_M(const float* __restrict__ Wr,  // [32][128]
                        const float* __restrict__ br,  // [32]
                        const float* __restrict__ Wk,  // [72][32]
                        const float* __restrict__ bk,  // [72]
                        float* __restrict__ MT,        // [128][72]
                        float* __restrict__ b2)        // [72]
{
    int idx = blockIdx.x * 256 + threadIdx.x;   // 36 blocks -> 9216
    if (idx < 72 * 128) {
        int o = idx >> 7, c = idx & 127;
        float s = 0.f;
        for (int r = 0; r < CR; ++r)
            s = fmaf(Wk[o * CR + r], Wr[r * C + c], s);
        MT[c * 72 + o] = s;
    }
    if (idx < 72) {
        float s = bk[idx];
        for (int r = 0; r < CR; ++r)
            s = fmaf(Wk[idx * CR + r], br[r], s);
        b2[idx] = s;
    }
}

// Zero-LDS, zero-sync kernel. Block = 256 threads = 4 waves x 64 pixels.
// Wave q owns groups {2q,2q+1} (18 kern outputs) and channels [32q,32q+32).
// kern comes straight from the 128 center pixels via MT (wave-uniform rows
// -> scalar s_loads, SMEM pipe). Stage-3 taps load directly from global
// (L1/L2 hits via the XCD swizzle). No LDS, no barriers, no fences:
// R6/R7 showed the LDS pipe + fence serialization was the wall, not occupancy.
__global__ __launch_bounds__(256) void invol_direct(
    const float* __restrict__ x,    // [B][C][130][130]
    const float* __restrict__ MT,   // [128][72]
    const float* __restrict__ b2,   // [72]
    float* __restrict__ out)        // [B][C][128][128]
{
    const int t = threadIdx.x;
    const int p = t & 63;
    const int q = __builtin_amdgcn_readfirstlane(t >> 6);

    // XCD-chunked swizzle (kept from R5: FETCH 190->58 MB).
    const int orig = blockIdx.x;
    const int blk  = (orig & 7) * 256 + (orig >> 3);   // bijective (2048 % 8 == 0)
    const int b    = blk >> 8;
    const int h    = (blk >> 1) & (HH - 1);
    const int w0   = (blk & 1) << 6;

    const float* xb = x + (size_t)b * C * CHW;
    const float* xc = xb + (size_t)(h + 1) * WIN + (w0 + p + 1);   // centers

    // ---- kern[18] = b2 + sum_c MT[c][18q..18q+18) * x_center[c] ----
    float kern[18];
#pragma unroll
    for (int k = 0; k < 18; ++k) kern[k] = b2[18 * q + k];

#pragma unroll
    for (int cb = 0; cb < 8; ++cb) {
        float xv[16];
#pragma unroll
        for (int cc = 0; cc < 16; ++cc)
            xv[cc] = xc[(size_t)(cb * 16 + cc) * CHW];
#pragma unroll
        for (int cc = 0; cc < 16; ++cc) {
            const float* m = MT + (cb * 16 + cc) * 72 + 18 * q;   // uniform -> s_load
#pragma unroll
            for (int k = 0; k < 18; ++k)
                kern[k] = fmaf(m[k], xv[cc], kern[k]);
        }
    }

    // ---- stage 3: 32 channels, 9 direct global taps each ----
    const float* xrow = xb + (size_t)h * WIN + (w0 + p);   // tap (0,0)
    float* op = out + (((size_t)(b * C + 32 * q)) * HH + h) * WW + w0 + p;

#pragma unroll
    for (int half = 0; half < 2; ++half) {      // group 2q+half, static kern slice
        float kh[9];
#pragma unroll
        for (int k = 0; k < 9; ++k) kh[k] = kern[9 * half + k];

#pragma unroll 4
        for (int cc = 0; cc < 16; ++cc) {
            const float* xp = xrow + (size_t)(32 * q + 16 * half + cc) * CHW;
            float tap[9];
#pragma unroll
            for (int i = 0; i < 3; ++i)
#pragma unroll
                for (int j = 0; j < 3; ++j)
                    tap[3 * i + j] = xp[i * WIN + j];
            float acc = 0.f;
#pragma unroll
            for (int k = 0; k < 9; ++k)
                acc = fmaf(kh[k], tap[k], acc);
            op[(size_t)(16 * half + cc) * HH * WW] = acc;
        }
    }
}
} // namespace

extern "C" void kernel_launch(void* const* d_in, const int* in_sizes, int n_in,
                              void* d_out, int out_size, void* d_ws, size_t ws_size,
                              hipStream_t stream) {
    const float* x     = (const float*)d_in[0];
    const float* Wred  = (const float*)d_in[1];
    const float* bred  = (const float*)d_in[2];
    const float* Wkern = (const float*)d_in[3];
    const float* bkern = (const float*)d_in[4];
    float* out = (float*)d_out;

    float* MT = (float*)d_ws;                  // 128*72*4 = 36864 B
    float* b2 = MT + 128 * 72;                 // +288 B

    build_M<<<36, 256, 0, stream>>>(Wred, bred, Wkern, bkern, MT, b2);

    // 8 b * 128 h * 2 wseg = 2048 blocks
    invol_direct<<<2048, 256, 0, stream>>>(x, MT, b2, out);
}

// Round 10
// 58.589 us; speedup vs baseline: 7.7640x; 7.7640x over previous
//
#include <hip/hip_runtime.h>

namespace {
constexpr int HIN = 130, WIN = 130;
constexpr int HH = 128, WW = 128;
constexpr int C = 128, CR = 32, B = 8;
constexpr int CHW = HIN * WIN;   // 16900

// Transpose W_reduce (32x128) -> WredT (128x32): the unrolled r-loop then
// reads contiguous uniform floats (compiler scalarizes to s_load_dwordx*).
__global__ void transpose_wred(const float* __restrict__ Wred, float* __restrict__ WredT) {
    int idx = blockIdx.x * 256 + threadIdx.x;   // 4096 elements
    int r = idx >> 7;
    int c = idx & 127;
    WredT[c * CR + r] = Wred[r * C + c];
}

// lgkm-only workgroup barrier: leaves global loads (vmcnt) in flight.
__device__ __forceinline__ void lgkm_barrier() {
    asm volatile("s_waitcnt lgkmcnt(0)\n\ts_barrier" ::: "memory");
    __builtin_amdgcn_sched_barrier(0);
}

// Block = 256 threads = 4 waves x 64 lanes; covers one FULL output row
// (128 px), 2 adjacent pixels per thread. Wave q owns groups {2q,2q+1} and
// channels [32q,32q+32).
//   stage1: partial red (8 dims) for both pixels -> red2 LDS, ONE barrier.
//   stage2: kern[18] x 2 pixels from red2 (b64 reads), registers only.
//   stage3: taps straight from global as aligned b64 pairs (4-col window
//           serves both pixels) -> L1/L2 is the sharing medium, zero LDS,
//           zero sync. R5-R7 showed the LDS pipe (~33us/CU) + fences were
//           the wall; this deletes ~85% of LDS traffic.
__global__ __launch_bounds__(256, 4) void invol_direct(
    const float* __restrict__ x,      // [B][C][130][130]
    const float* __restrict__ WredT,  // [128][32]
    const float* __restrict__ bred,   // [32]
    const float* __restrict__ Wkern,  // [72][32]
    const float* __restrict__ bkern,  // [72]
    float* __restrict__ out)          // [B][C][128][128]
{
    __shared__ float red2[CR][128];   // [r][pixel], b64-friendly, 16 KB

    const int t = threadIdx.x;
    const int p = t & 63;
    const int q = __builtin_amdgcn_readfirstlane(t >> 6);

    // XCD-chunked swizzle: XCD k owns a contiguous blk range -> h-adjacent
    // blocks (sharing 2/3 tap rows) land on the same L2. 1024 % 8 == 0.
    const int orig = blockIdx.x;
    const int blk  = (orig & 7) * 128 + (orig >> 3);
    const int b    = blk >> 7;
    const int h    = blk & (HH - 1);

    const float* xb = x + (size_t)b * C * CHW;

    // ---- stage 1: red[8q..8q+8) for pixels 2p, 2p+1 ----
    // centers: input row h+1, cols 2p+1 and 2p+2
    const float* xc = xb + (size_t)(h + 1) * WIN + (2 * p + 1);
    float r0[8], r1[8];
#pragma unroll
    for (int r = 0; r < 8; ++r) { r0[r] = bred[q * 8 + r]; r1[r] = r0[r]; }

#pragma unroll
    for (int cb = 0; cb < 4; ++cb) {
        float xv0[32], xv1[32];
#pragma unroll
        for (int cc = 0; cc < 32; ++cc) {
            const float* cp = xc + (size_t)(cb * 32 + cc) * CHW;
            xv0[cc] = cp[0];
            xv1[cc] = cp[1];
        }
#pragma unroll
        for (int cc = 0; cc < 32; ++cc) {
#pragma unroll
            for (int r = 0; r < 8; ++r) {
                float wgt = WredT[(cb * 32 + cc) * CR + q * 8 + r];
                r0[r] = fmaf(wgt, xv0[cc], r0[r]);
                r1[r] = fmaf(wgt, xv1[cc], r1[r]);
            }
        }
    }
    // write as b64 pairs: red2[r][2p], red2[r][2p+1]
#pragma unroll
    for (int r = 0; r < 8; ++r)
        *(float2*)&red2[q * 8 + r][2 * p] = make_float2(r0[r], r1[r]);

    lgkm_barrier();   // red2 visible to all waves; no vmcnt drain

    // ---- stage 2: kern[18] per pixel for groups {2q,2q+1} ----
    float k0[18], k1[18];
#pragma unroll
    for (int k = 0; k < 18; ++k) { k0[k] = bkern[18 * q + k]; k1[k] = k0[k]; }
#pragma unroll
    for (int r = 0; r < CR; ++r) {
        float2 rv = *(const float2*)&red2[r][2 * p];
#pragma unroll
        for (int k = 0; k < 18; ++k) {
            float wgt = Wkern[(18 * q + k) * CR + r];
            k0[k] = fmaf(wgt, rv.x, k0[k]);
            k1[k] = fmaf(wgt, rv.y, k1[k]);
        }
    }

    // ---- stage 3: 32 channels (32q..32q+31), taps direct from global ----
    // window cols 2p..2p+3 of rows h..h+2 serve both pixels
    const float* xrow = xb + (size_t)h * WIN + 2 * p;
    float* op = out + (((size_t)(b * C + 32 * q)) * HH + h) * WW + 2 * p;

#pragma unroll
    for (int half = 0; half < 2; ++half) {   // group 2q+half, static kern slice
        float kh0[9], kh1[9];
#pragma unroll
        for (int k = 0; k < 9; ++k) { kh0[k] = k0[9 * half + k]; kh1[k] = k1[9 * half + k]; }

#pragma unroll 2
        for (int cc = 0; cc < 16; ++cc) {
            const float* xp = xrow + (size_t)(32 * q + 16 * half + cc) * CHW;
            float2 ta[3], tb[3];
#pragma unroll
            for (int i = 0; i < 3; ++i) {
                ta[i] = *(const float2*)(xp + i * WIN);       // cols 2p,2p+1
                tb[i] = *(const float2*)(xp + i * WIN + 2);   // cols 2p+2,2p+3
            }
            float a0 = 0.f, a1 = 0.f;
#pragma unroll
            for (int i = 0; i < 3; ++i) {
                a0 = fmaf(kh0[3 * i + 0], ta[i].x, a0);
                a0 = fmaf(kh0[3 * i + 1], ta[i].y, a0);
                a0 = fmaf(kh0[3 * i + 2], tb[i].x, a0);
                a1 = fmaf(kh1[3 * i + 0], ta[i].y, a1);
                a1 = fmaf(kh1[3 * i + 1], tb[i].x, a1);
                a1 = fmaf(kh1[3 * i + 2], tb[i].y, a1);
            }
            *(float2*)(op + (size_t)(16 * half + cc) * HH * WW) = make_float2(a0, a1);
        }
    }
}
} // namespace

extern "C" void kernel_launch(void* const* d_in, const int* in_sizes, int n_in,
                              void* d_out, int out_size, void* d_ws, size_t ws_size,
                              hipStream_t stream) {
    const float* x     = (const float*)d_in[0];
    const float* Wred  = (const float*)d_in[1];
    const float* bred  = (const float*)d_in[2];
    const float* Wkern = (const float*)d_in[3];
    const float* bkern = (const float*)d_in[4];
    float* out   = (float*)d_out;
    float* WredT = (float*)d_ws;   // 16 KB scratch

    transpose_wred<<<16, 256, 0, stream>>>(Wred, WredT);

    // 8 b * 128 h = 1024 blocks, one full output row each
    invol_direct<<<1024, 256, 0, stream>>>(x, WredT, bred, Wkern, bkern, out);
}